// Round 3
// baseline (687.795 us; speedup 1.0000x reference)
//
#include <hip/hip_runtime.h>

#define INVALID_TOKEN_ID -1

typedef float f32x4 __attribute__((ext_vector_type(4)));

// SEGS blocks per row, 256 threads each. Each block argmaxes a contiguous
// ~128 KB segment of one row and writes a (val, idx) partial to workspace.
//
// Main loop tracks MAX ONLY (4-way max tree per float4 + record the winning
// float4-index on strict improvement): ~6 VALU/16B vs ~14 for full argmax
// tracking, and no long cmp->cndmask dependent chain. Exact element index is
// reconstructed afterwards by re-loading the (at most 4) winning float4s per
// thread. Strict '>' + in-order equality resolution keeps jnp.argmax
// first-occurrence semantics (fp32 max selects an input bit-exactly).
//
// ~45 VGPRs -> __launch_bounds__(256,8) gives true 32 waves/CU (the previous
// (256,4) config allowed 128 VGPR and only guaranteed 16 waves/CU).
__global__ __launch_bounds__(256, 8) void rowargmax_part(
    const float* __restrict__ logits, float* __restrict__ pval,
    int* __restrict__ pidx, int vocab, int segs) {
    const int row = blockIdx.x / segs;
    const int seg = blockIdx.x - row * segs;
    const int t = threadIdx.x;

    const float* rowp = logits + (size_t)row * (size_t)vocab;
    const f32x4* rowv = (const f32x4*)rowp;
    const int nvec = vocab >> 2;
    const int segLen = (nvec + segs - 1) / segs;
    const int begin = seg * segLen;
    const int end = min(begin + segLen, nvec);

    float m0 = -__builtin_inff(), m1 = m0, m2 = m0, m3 = m0;
    int r0 = -1, r1 = -1, r2 = -1, r3 = -1;

    int i = begin + t;
    // 4 independent streams, 4 KB apart; 16 KB per block-iter
    for (; i + 768 < end; i += 1024) {
        f32x4 a = rowv[i];
        f32x4 b = rowv[i + 256];
        f32x4 c = rowv[i + 512];
        f32x4 d = rowv[i + 768];
        float la = fmaxf(fmaxf(a[0], a[1]), fmaxf(a[2], a[3]));
        float lb = fmaxf(fmaxf(b[0], b[1]), fmaxf(b[2], b[3]));
        float lc = fmaxf(fmaxf(c[0], c[1]), fmaxf(c[2], c[3]));
        float ld = fmaxf(fmaxf(d[0], d[1]), fmaxf(d[2], d[3]));
        if (la > m0) { m0 = la; r0 = i; }
        if (lb > m1) { m1 = lb; r1 = i + 256; }
        if (lc > m2) { m2 = lc; r2 = i + 512; }
        if (ld > m3) { m3 = ld; r3 = i + 768; }
    }
    // remainder (indices here exceed all stream indices -> strict '>' is safe)
    for (; i < end; i += 256) {
        f32x4 a = rowv[i];
        float la = fmaxf(fmaxf(a[0], a[1]), fmaxf(a[2], a[3]));
        if (la > m0) { m0 = la; r0 = i; }
    }

    // reconstruct exact element index per stream, then merge (value, then
    // lower index wins -> first occurrence). Re-load cost: <=4 float4/thread.
    float best = -__builtin_inff();
    int idx = 0x7fffffff;
    float mv[4] = {m0, m1, m2, m3};
    int rv[4] = {r0, r1, r2, r3};
    #pragma unroll
    for (int s = 0; s < 4; ++s) {
        if (rv[s] >= 0) {
            f32x4 v = rowv[rv[s]];
            const float m = mv[s];
            const int base = rv[s] << 2;
            int j = base;  // descending checks: first (lowest) match wins
            if (v[3] == m) j = base + 3;
            if (v[2] == m) j = base + 2;
            if (v[1] == m) j = base + 1;
            if (v[0] == m) j = base;
            if (m > best || (m == best && j < idx)) { best = m; idx = j; }
        }
    }

    // scalar tail (vocab % 4) belongs to the last segment; tail idx > all vector idx
    if (seg == segs - 1) {
        for (int j = (nvec << 2) + t; j < vocab; j += 256) {
            float v = rowp[j];
            if (v > best) { best = v; idx = j; }
        }
    }

    // wave (64-lane) butterfly reduction; ties -> lower index
    #pragma unroll
    for (int off = 32; off > 0; off >>= 1) {
        float ov = __shfl_down(best, off, 64);
        int oi = __shfl_down(idx, off, 64);
        if (ov > best || (ov == best && oi < idx)) { best = ov; idx = oi; }
    }

    __shared__ float svals[4];
    __shared__ int sidx[4];
    const int wave = t >> 6;
    if ((t & 63) == 0) { svals[wave] = best; sidx[wave] = idx; }
    __syncthreads();
    if (t == 0) {
        #pragma unroll
        for (int w = 1; w < 4; ++w) {
            if (svals[w] > best || (svals[w] == best && sidx[w] < idx)) {
                best = svals[w]; idx = sidx[w];
            }
        }
        const int p = row * segs + seg;
        pval[p] = best;
        pidx[p] = idx;
    }
}

// One thread per batch row: merge segment partials (value, then lower index ->
// first-occurrence preserved), then cumulative accept + bonus position.
__global__ void finalize_kernel(const float* __restrict__ pval,
                                const int* __restrict__ pidx,
                                const int* __restrict__ spec,
                                int* __restrict__ out, int B, int k, int segs) {
    int b = blockIdx.x * blockDim.x + threadIdx.x;
    if (b >= B) return;
    const int kp1 = k + 1;

    int outv[8];
    int gen[8];
    #pragma unroll
    for (int j = 0; j < 8; ++j) { outv[j] = 0; gen[j] = 0; }

    for (int j = 0; j < kp1; ++j) {
        const int tok = b * kp1 + j;
        float bv = pval[tok * segs];
        int bi = pidx[tok * segs];
        for (int s = 1; s < segs; ++s) {
            float v = pval[tok * segs + s];
            int ix = pidx[tok * segs + s];
            if (v > bv || (v == bv && ix < bi)) { bv = v; bi = ix; }
        }
        outv[j] = bi;
    }

    int acc = 1;
    int firstZero = k;  // if all k drafts accepted, bonus at position k
    for (int j = 0; j < k; ++j) {
        if (acc && outv[j] != spec[b * k + j]) { acc = 0; firstZero = j; }
        gen[j] = acc;
    }
    gen[k] = 0;
    gen[firstZero] = 1;  // first rejected / bonus position

    for (int j = 0; j < kp1; ++j)
        out[b * kp1 + j] = gen[j] ? outv[j] : INVALID_TOKEN_ID;
}

extern "C" void kernel_launch(void* const* d_in, const int* in_sizes, int n_in,
                              void* d_out, int out_size, void* d_ws, size_t ws_size,
                              hipStream_t stream) {
    const float* logits = (const float*)d_in[0];
    const int* spec = (const int*)d_in[1];
    int* out = (int*)d_out;

    const int total_tokens = out_size;                 // B*(k+1) = 1024
    const int vocab = in_sizes[0] / total_tokens;      // 128000
    const int B = out_size - in_sizes[1];              // B*(k+1) - B*k = 128
    const int k = in_sizes[1] / B;                     // 7

    const int SEGS = 4;  // blocks per row; each streams a contiguous ~128 KB
    float* pval = (float*)d_ws;                        // total_tokens*SEGS floats
    int* pidx = (int*)(pval + total_tokens * SEGS);    // total_tokens*SEGS ints

    rowargmax_part<<<total_tokens * SEGS, 256, 0, stream>>>(logits, pval, pidx, vocab, SEGS);
    finalize_kernel<<<(B + 127) / 128, 128, 0, stream>>>(pval, pidx, spec, out, B, k, SEGS);
}